// Round 1
// baseline (42.182 us; speedup 1.0000x reference)
//
#include <hip/hip_runtime.h>

// Problem constants (match the reference)
#define T_DIM 160
#define B_DIM 64
#define C_DIM 6625
#define S_DIM 25
#define L_DIM 51            // 2*S+1
#define NEGV  (-1e30f)

// One block per batch element. 256 threads stage emissions into LDS;
// wave 0 runs the sequential CTC alpha recurrence with lane l = lattice pos.
__global__ __launch_bounds__(256)
void ctc_alpha_kernel(const float* __restrict__ preds,     // [T,B,C]
                      const int*   __restrict__ targets,   // [B,S]
                      const int*   __restrict__ tlen,      // [B]
                      float*       __restrict__ per_b)     // [B] out
{
    const int b   = blockIdx.x;
    const int tid = threadIdx.x;

    __shared__ float emit_s[T_DIM * L_DIM];   // 160*51*4 = 32640 B
    __shared__ int   ext_s[L_DIM];

    // Build extended-target class indices: even -> blank(0), odd -> targets[(l-1)/2]
    if (tid < L_DIM) {
        int cls = 0;
        if (tid & 1) cls = targets[b * S_DIM + (tid >> 1)];
        ext_s[tid] = cls;
    }
    __syncthreads();

    // Stage all emissions: emit_s[t*L + l] = preds[t, b, ext[l]]
    // 8160 independent scattered 4B loads spread over 256 threads.
    {
        const size_t row_stride = (size_t)B_DIM * C_DIM;
        const float* pb = preds + (size_t)b * C_DIM;
        for (int flat = tid; flat < T_DIM * L_DIM; flat += 256) {
            int t = flat / L_DIM;
            int l = flat - t * L_DIM;
            emit_s[flat] = pb[(size_t)t * row_stride + ext_s[l]];
        }
    }
    __syncthreads();

    if (tid >= 64) return;      // recurrence on wave 0 only (no further barriers)

    const int l = tid;                 // lattice position, lanes 51..63 idle
    const bool active = (l < L_DIM);
    const int  len = tlen[b];

    // skip transition allowed at odd l>=3 with distinct consecutive labels
    bool skip = false;
    if (active && (l & 1) && l >= 3) {
        int i = l >> 1;                // l = 2i+1 -> i = (l-1)/2
        skip = (targets[b * S_DIM + i] != targets[b * S_DIM + i - 1]);
    }

    float alpha = NEGV;
    if (l == 0) alpha = emit_s[0];
    if (l == 1) alpha = emit_s[1];

    for (int t = 1; t < T_DIM; ++t) {
        float a1 = alpha;
        float a2 = __shfl_up(alpha, 1, 64);
        float a3 = __shfl_up(alpha, 2, 64);
        if (l < 1)  a2 = NEGV;
        if (!skip)  a3 = NEGV;
        float m = fmaxf(fmaxf(a1, a2), a3);
        float v = m + logf(expf(a1 - m) + expf(a2 - m) + expf(a3 - m));
        float e = active ? emit_s[t * L_DIM + l] : NEGV;
        alpha = v + e;
    }

    // nll = -logaddexp(alpha[2*len], alpha[2*len-1])
    const int idx = 2 * len;                  // in [10, 50]
    float l_last = __shfl(alpha, idx, 64);
    float l_prev = __shfl(alpha, idx - 1, 64);
    if (l == 0) {
        float m  = fmaxf(l_last, l_prev);
        float nll = -(m + logf(expf(l_last - m) + expf(l_prev - m)));
        float per = (nll >= 1e29f) ? 0.0f : nll / (float)len;
        per_b[b] = per;
    }
}

// Mean over B=64 per-sample losses.
__global__ __launch_bounds__(64)
void ctc_reduce_kernel(const float* __restrict__ per_b, float* __restrict__ out)
{
    float v = per_b[threadIdx.x];
    #pragma unroll
    for (int off = 32; off > 0; off >>= 1)
        v += __shfl_down(v, off, 64);
    if (threadIdx.x == 0) out[0] = v / (float)B_DIM;
}

extern "C" void kernel_launch(void* const* d_in, const int* in_sizes, int n_in,
                              void* d_out, int out_size, void* d_ws, size_t ws_size,
                              hipStream_t stream)
{
    const float* preds   = (const float*)d_in[0];   // [T,B,C] fp32
    const int*   targets = (const int*)d_in[1];     // [B,S]
    const int*   tlen    = (const int*)d_in[2];     // [B]
    float* out  = (float*)d_out;                    // scalar
    float* perb = (float*)d_ws;                     // 64 floats scratch

    ctc_alpha_kernel<<<B_DIM, 256, 0, stream>>>(preds, targets, tlen, perb);
    ctc_reduce_kernel<<<1, 64, 0, stream>>>(perb, out);
}

// Round 2
// 34.299 us; speedup vs baseline: 1.2298x; 1.2298x over previous
//
#include <hip/hip_runtime.h>

// Problem constants (match the reference)
#define T_DIM 160
#define B_DIM 64
#define C_DIM 6625
#define S_DIM 25
#define L_DIM 51            // 2*S+1
#define NEGV  (-1.0e30f)
#define LOG2E 1.4426950408889634f
#define LN2   0.6931471805599453f
#define CHUNK  16
#define NCHUNK (T_DIM / CHUNK)   // 10

// One block per batch element.
//  - wave 0 (lanes 0..63): CTC alpha recurrence, lane l = lattice position,
//    in log2 domain (exp2f/log2f -> native v_exp_f32/v_log_f32).
//  - waves 1..3 (192 threads): gather chunk c+1 emissions into LDS while
//    wave 0 computes chunk c (emissions pre-scaled by log2(e) at staging).
__global__ __launch_bounds__(256)
void ctc_alpha_fused(const float* __restrict__ preds,     // [T,B,C]
                     const int*   __restrict__ targets,   // [B,S]
                     const int*   __restrict__ tlen,      // [B]
                     float*       __restrict__ out)       // scalar (pre-zeroed)
{
    const int b   = blockIdx.x;
    const int tid = threadIdx.x;

    __shared__ float emit_s[T_DIM * L_DIM];   // 32640 B
    __shared__ int   ext_s[L_DIM];

    // Extended-target class ids: even -> blank(0), odd -> targets[(l-1)/2]
    if (tid < L_DIM) {
        int cls = (tid & 1) ? targets[b * S_DIM + (tid >> 1)] : 0;
        ext_s[tid] = cls;
    }
    __syncthreads();

    const size_t row_stride = (size_t)B_DIM * C_DIM;
    const float* pb = preds + (size_t)b * C_DIM;

    // Prologue: stage chunk 0 (t in [0,16)) with all 256 threads
    for (int flat = tid; flat < CHUNK * L_DIM; flat += 256) {
        int t = flat / L_DIM;
        int l = flat - t * L_DIM;
        emit_s[flat] = pb[(size_t)t * row_stride + ext_s[l]] * LOG2E;
    }
    __syncthreads();

    // Per-lane recurrence state (wave 0)
    const int l = tid;                         // lattice position for tid<64
    const int l_eff = (l < L_DIM) ? l : (L_DIM - 1);
    const int addr1 = ((l >= 1) ? l - 1 : 0) << 2;   // ds_bpermute byte addrs
    const int addr2 = ((l >= 2) ? l - 2 : 0) << 2;
    bool skipf = false;
    if (tid < 64 && (l & 1) && l >= 3 && l < L_DIM) {
        int i = l >> 1;
        skipf = (targets[b * S_DIM + i] != targets[b * S_DIM + i - 1]);
    }
    float alpha = NEGV;                        // log2-domain alpha
    if (tid == 0) alpha = emit_s[0];
    if (tid == 1) alpha = emit_s[1];

    int t = 1;
    for (int c = 0; c < NCHUNK; ++c) {
        if (tid >= 64) {
            // stage chunk c+1 while wave 0 computes chunk c
            if (c + 1 < NCHUNK) {
                const int base = (c + 1) * CHUNK * L_DIM;
                const int t0   = (c + 1) * CHUNK;
                for (int flat = tid - 64; flat < CHUNK * L_DIM; flat += 192) {
                    int tt = flat / L_DIM;
                    int ll = flat - tt * L_DIM;
                    emit_s[base + flat] =
                        pb[(size_t)(t0 + tt) * row_stride + ext_s[ll]] * LOG2E;
                }
            }
        } else {
            const int tend = (c + 1) * CHUNK;
            for (; t < tend; ++t) {
                float a1 = alpha;
                float a2 = __int_as_float(
                    __builtin_amdgcn_ds_bpermute(addr1, __float_as_int(alpha)));
                float a3 = __int_as_float(
                    __builtin_amdgcn_ds_bpermute(addr2, __float_as_int(alpha)));
                if (l < 1)  a2 = NEGV;
                if (!skipf) a3 = NEGV;
                float m = fmaxf(fmaxf(a1, a2), a3);
                float s = exp2f(a1 - m) + exp2f(a2 - m) + exp2f(a3 - m);
                alpha = m + log2f(s) + emit_s[t * L_DIM + l_eff];
            }
        }
        __syncthreads();
    }

    // Endpoints: nll = -ln2 * log2addexp2(alpha[2*len], alpha[2*len-1])
    if (tid < 64) {
        const int len = tlen[b];
        const int idx = 2 * len;               // in [10, 50]
        float l_last = __shfl(alpha, idx, 64);
        float l_prev = __shfl(alpha, idx - 1, 64);
        if (tid == 0) {
            float m   = fmaxf(l_last, l_prev);
            float r2  = m + log2f(exp2f(l_last - m) + exp2f(l_prev - m));
            float nll = -r2 * LN2;
            float per = (nll >= 1e29f) ? 0.0f : nll / (float)len;
            atomicAdd(out, per * (1.0f / B_DIM));
        }
    }
}

extern "C" void kernel_launch(void* const* d_in, const int* in_sizes, int n_in,
                              void* d_out, int out_size, void* d_ws, size_t ws_size,
                              hipStream_t stream)
{
    const float* preds   = (const float*)d_in[0];   // [T,B,C] fp32
    const int*   targets = (const int*)d_in[1];     // [B,S]
    const int*   tlen    = (const int*)d_in[2];     // [B]
    float* out = (float*)d_out;                     // scalar

    hipMemsetAsync(out, 0, sizeof(float), stream);  // out accumulates atomically
    ctc_alpha_fused<<<B_DIM, 256, 0, stream>>>(preds, targets, tlen, out);
}